// Round 12
// baseline (50.185 us; speedup 1.0000x reference)
//
#include <hip/hip_runtime.h>
#include <math.h>

#define SF 0.99999f
#define PI2 6.283185307179586476925f
#define SWZ(c) ((c) ^ (((c) >> 4) & 15))
// compiler-only fence: orders same-wave LDS write/read phases (HW LDS pipe is
// in-order per wave; this stops compiler reordering).
#define LDSFENCE() asm volatile("" ::: "memory")

template<int SGN>
__device__ __forceinline__ void twmul(float& ur, float& ui, float c, float s) {
    const float ss = (SGN < 0) ? -s : s;
    const float r = ur * c - ui * ss;
    const float i = ui * c + ur * ss;
    ur = r; ui = i;
}

// 8-point DFT across registers. SGN=-1: forward; SGN=+1: inverse.
template<int SGN>
__device__ __forceinline__ void bfly8(float* ur, float* ui) {
    const float C2 = 0.70710678118654752440f;
    float ar[4], ai[4], br[4], bi[4];
#pragma unroll
    for (int m = 0; m < 4; ++m) {
        ar[m] = ur[m] + ur[m + 4]; ai[m] = ui[m] + ui[m + 4];
        br[m] = ur[m] - ur[m + 4]; bi[m] = ui[m] - ui[m + 4];
    }
    float b1r, b1i, b2r, b2i, b3r, b3i;
    if (SGN < 0) {
        b1r = C2 * (br[1] + bi[1]); b1i = C2 * (bi[1] - br[1]);
        b2r = bi[2];                b2i = -br[2];
        b3r = C2 * (bi[3] - br[3]); b3i = -C2 * (br[3] + bi[3]);
    } else {
        b1r = C2 * (br[1] - bi[1]); b1i = C2 * (bi[1] + br[1]);
        b2r = -bi[2];               b2i = br[2];
        b3r = -C2 * (br[3] + bi[3]); b3i = C2 * (br[3] - bi[3]);
    }
    const float e0r = ar[0] + ar[2], e0i = ai[0] + ai[2];
    const float e1r = ar[0] - ar[2], e1i = ai[0] - ai[2];
    const float o0r = ar[1] + ar[3], o0i = ai[1] + ai[3];
    const float o1r = ar[1] - ar[3], o1i = ai[1] - ai[3];
    ur[0] = e0r + o0r; ui[0] = e0i + o0i;
    ur[4] = e0r - o0r; ui[4] = e0i - o0i;
    if (SGN < 0) { ur[2] = e1r + o1i; ui[2] = e1i - o1r; ur[6] = e1r - o1i; ui[6] = e1i + o1r; }
    else         { ur[2] = e1r - o1i; ui[2] = e1i + o1r; ur[6] = e1r + o1i; ui[6] = e1i - o1r; }
    const float f0r = br[0] + b2r, f0i = bi[0] + b2i;
    const float f1r = br[0] - b2r, f1i = bi[0] - b2i;
    const float g0r = b1r + b3r, g0i = b1i + b3i;
    const float g1r = b1r - b3r, g1i = b1i - b3i;
    ur[1] = f0r + g0r; ui[1] = f0i + g0i;
    ur[5] = f0r - g0r; ui[5] = f0i - g0i;
    if (SGN < 0) { ur[3] = f1r + g1i; ui[3] = f1i - g1r; ur[7] = f1r - g1i; ui[7] = f1i + g1r; }
    else         { ur[3] = f1r - g1i; ui[3] = f1i + g1r; ur[7] = f1r + g1i; ui[7] = f1i - g1r; }
}

// Wave-local 512-pt complex FFT, Stockham radix-8, 3 stages, single LDS buffer.
// ra[8] = hoisted read indices SWZ(t+64m). Writes per-element inline SWZ.
// No barriers (single-wave workgroup; LDS ops retire in order per wave).
template<int SGN>
__device__ __forceinline__ void fft512w(float* ur, float* ui,
                                        float2* __restrict__ buf,
                                        const float2* __restrict__ tw2,
                                        const float2* __restrict__ tw3,
                                        const int* ra, int t) {
    bfly8<SGN>(ur, ui);
    LDSFENCE();
#pragma unroll
    for (int m = 0; m < 8; ++m) buf[SWZ(8 * t + m)] = make_float2(ur[m], ui[m]);
    LDSFENCE();
#pragma unroll
    for (int m = 0; m < 8; ++m) { const float2 v = buf[ra[m]]; ur[m] = v.x; ui[m] = v.y; }
    const int k2 = t & 7;
#pragma unroll
    for (int m = 1; m < 8; ++m) { const float2 w = tw2[m * 8 + k2]; twmul<SGN>(ur[m], ui[m], w.x, w.y); }
    bfly8<SGN>(ur, ui);
    const int jj = ((t >> 3) << 6) + k2;
    LDSFENCE();
#pragma unroll
    for (int m = 0; m < 8; ++m) buf[SWZ(jj + 8 * m)] = make_float2(ur[m], ui[m]);
    LDSFENCE();
#pragma unroll
    for (int m = 0; m < 8; ++m) { const float2 v = buf[ra[m]]; ur[m] = v.x; ui[m] = v.y; }
#pragma unroll
    for (int m = 1; m < 8; ++m) { const float2 w = tw3[m * 64 + t]; twmul<SGN>(ur[m], ui[m], w.x, w.y); }
    bfly8<SGN>(ur, ui);
    LDSFENCE();
}

// ONE WAVE PER BLOCK: residency experiment. No __syncthreads anywhere.
__global__ __launch_bounds__(64, 4) void pbfd_kernel(
    const float* __restrict__ g_mic,   // (B,256)
    const float* __restrict__ g_lsb,   // (B,1280)
    const float* __restrict__ g_phie,  // (B,257)
    const float* __restrict__ g_p1,    // (B,257,4)
    const float* __restrict__ g_hr,    // (B,257,4)
    const float* __restrict__ g_hi,    // (B,257,4)
    float* __restrict__ g_out)         // (B,256)
{
    __shared__ float2 tw2[64];
    __shared__ float2 tw3[512];
    __shared__ float2 xch[512];

    const int t = threadIdx.x;         // 0..63
    const int elem = blockIdx.x;
    float2* buf = &xch[0];
    const int ml = (64 - t) & 63;  // mirror lane: bin 512-k lives at (ml, 7-m) for t>=1

    // ---- per-block twiddle tables, built by this wave (no barrier needed) ----
    // tw3[m*64+t] = e^{+2pi i m t/512} via 7 iterated cmuls (accuracy validated R7);
    // tw2[l] = e^{+2pi i (l>>3)(l&7)/64}, one entry per lane.
    {
        float s3, c3;
        sincosf(PI2 * (float)t * (1.0f / 512.0f), &s3, &c3);
        float cr = 1.f, ci = 0.f;
#pragma unroll
        for (int m = 0; m < 8; ++m) {
            tw3[m * 64 + t] = make_float2(cr, ci);
            const float nr = cr * c3 - ci * s3;
            ci = ci * c3 + cr * s3;
            cr = nr;
        }
        float s2, c2;
        sincosf(PI2 * (float)((t >> 3) * (t & 7)) * (1.0f / 64.0f), &s2, &c2);
        tw2[t] = make_float2(c2, s2);
    }
    LDSFENCE();

    // ---- hoisted LDS read indices (invariant across all 9 FFTs) ----
    int ra[8];
#pragma unroll
    for (int m = 0; m < 8; ++m) ra[m] = SWZ(t + 64 * m);

    float mv[4];
    {
        const float* mp = g_mic + (size_t)elem * 256;
#pragma unroll
        for (int q = 0; q < 4; ++q) mv[q] = mp[t + 64 * q];
    }

    // ---- X: 4 real frame-FFTs as 2 paired complex FFTs; keep low bins + lane0 Nyquist ----
    float xr[4][4], xi[4][4], xn[4];
    {
        const float* lb = g_lsb + (size_t)elem * 1280;
#pragma unroll
        for (int pr = 0; pr < 2; ++pr) {
            float ur[8], ui[8];
#pragma unroll
            for (int m = 0; m < 8; ++m) {
                ur[m] = lb[(2 * pr) * 256 + t + 64 * m];
                ui[m] = lb[(2 * pr + 1) * 256 + t + 64 * m];
            }
            fft512w<-1>(ur, ui, buf, tw2, tw3, ra, t);
#pragma unroll
            for (int m = 0; m < 4; ++m) {
                float zmr = __shfl(ur[7 - m], ml);
                float zmi = __shfl(ui[7 - m], ml);
                if (t == 0) {  // lane0: mirror of bin 64m is slot 8-m (self for m=0)
                    zmr = (m == 0) ? ur[0] : ur[8 - m];
                    zmi = (m == 0) ? ui[0] : ui[8 - m];
                }
                xr[2 * pr][m]     = 0.5f * (ur[m] + zmr);
                xi[2 * pr][m]     = 0.5f * (ui[m] - zmi);
                xr[2 * pr + 1][m] = 0.5f * (ui[m] + zmi);
                xi[2 * pr + 1][m] = -0.5f * (ur[m] - zmr);
            }
            if (t == 0) { xn[2 * pr] = ur[4]; xn[2 * pr + 1] = ui[4]; }  // X[256] re/im-packed
        }
    }

    // Hermitian IFFT of a low-half spectrum (cr/ci low slots + lane0 Nyquist cn):
    // o4[q] = Re(ifft)[256+t+64q]/512.
    auto herm_ifft = [&](const float cr[4], const float ci[4], float cn, float o4[4]) {
        float ur[8], ui[8];
#pragma unroll
        for (int m = 0; m < 4; ++m) { ur[m] = cr[m]; ui[m] = ci[m]; }
#pragma unroll
        for (int m = 4; m < 8; ++m) {  // high slot = conj(mirror-lane low slot 7-m)
            ur[m] = __shfl(cr[7 - m], ml);
            ui[m] = -__shfl(ci[7 - m], ml);
        }
        if (t == 0) {
            ur[5] = cr[3]; ui[5] = -ci[3];
            ur[6] = cr[2]; ui[6] = -ci[2];
            ur[7] = cr[1]; ui[7] = -ci[1];
            ur[4] = cn; ui[4] = 0.f;  // Nyquist: real
        }
        fft512w<1>(ur, ui, buf, tw2, tw3, ra, t);
#pragma unroll
        for (int q = 0; q < 4; ++q) o4[q] = ur[4 + q] * (1.0f / 512.0f);
    };

    // ---- est (H prior): C = sum_j X*H; d = mic - est.  H dies after this block. ----
    float d4[4];
    float pn[4], en = 0.f, pen = 0.f;  // lane0 side channel
    {
        float hr_[4][4], hi_[4][4], hn[4];
        {
            const float4* hr4 = (const float4*)g_hr + (size_t)elem * 257;
            const float4* hi4 = (const float4*)g_hi + (size_t)elem * 257;
#pragma unroll
            for (int m = 0; m < 4; ++m) {
                const float4 a = hr4[t + 64 * m];
                hr_[0][m] = a.x; hr_[1][m] = a.y; hr_[2][m] = a.z; hr_[3][m] = a.w;
            }
#pragma unroll
            for (int m = 0; m < 4; ++m) {
                const float4 b = hi4[t + 64 * m];
                hi_[0][m] = b.x; hi_[1][m] = b.y; hi_[2][m] = b.z; hi_[3][m] = b.w;
            }
            if (t == 0) {
                const float4 a = hr4[256];
                const float4 p = ((const float4*)g_p1)[(size_t)elem * 257 + 256];
                hn[0] = a.x; hn[1] = a.y; hn[2] = a.z; hn[3] = a.w;
                pn[0] = p.x; pn[1] = p.y; pn[2] = p.z; pn[3] = p.w;
            }
        }
        float cr[4], ci[4], cn = 0.f;
#pragma unroll
        for (int m = 0; m < 4; ++m) {
            float sr = 0.f, si = 0.f;
#pragma unroll
            for (int j = 0; j < 4; ++j) {
                sr += xr[j][m] * hr_[j][m] - xi[j][m] * hi_[j][m];
                si += xr[j][m] * hi_[j][m] + xi[j][m] * hr_[j][m];
            }
            cr[m] = sr; ci[m] = si;
        }
        if (t == 0) {
#pragma unroll
            for (int j = 0; j < 4; ++j) cn += xn[j] * hn[j];
        }
        float o4[4];
        herm_ifft(cr, ci, cn, o4);
#pragma unroll
        for (int q = 0; q < 4; ++q) d4[q] = mv[q] - o4[q];
    }

    // ---- E = FFT([zeros(256); d]) ----
    float er[4], ei[4];
    {
        float ur[8], ui[8];
#pragma unroll
        for (int m = 0; m < 4; ++m) { ur[m] = 0.f; ui[m] = 0.f; }
#pragma unroll
        for (int q = 0; q < 4; ++q) { ur[4 + q] = d4[q]; ui[4 + q] = 0.f; }
        fft512w<-1>(ur, ui, buf, tw2, tw3, ra, t);
#pragma unroll
        for (int m = 0; m < 4; ++m) { er[m] = ur[m]; ei[m] = ui[m]; }
        if (t == 0) en = ur[4];
    }

    // ---- phi_e ----
    float pe[4];
    {
        const float* php = g_phie + (size_t)elem * 257;
#pragma unroll
        for (int m = 0; m < 4; ++m)
            pe[m] = 0.7f * php[t + 64 * m] + 0.3f * (er[m] * er[m] + ei[m] * ei[m]);
        if (t == 0) pen = 0.7f * php[256] + 0.3f * en * en;
    }

    // ---- gradient: pairs (0,1),(2,3): IFFT(KE0+i*KE1) -> mask -> FFT ->
    //      unpack fd_dH and accumulate D = sum_j X_j * fd_dH_j on the fly ----
    float Dr[4] = {0, 0, 0, 0}, Di[4] = {0, 0, 0, 0};
    float dn = 0.f;  // lane0: D at Nyquist
    {
        const float4* p14 = (const float4*)g_p1 + (size_t)elem * 257;
#pragma unroll
        for (int pr = 0; pr < 2; ++pr) {
            const int j0 = 2 * pr, j1 = 2 * pr + 1;
            float ur[8], ui[8], gr[4], gi[4];
#pragma unroll
            for (int m = 0; m < 4; ++m) {
                // KE_j = P1_j * conj(X_j) / R_j * E  (P1 reloaded here, cache-hot)
                const float4 p = p14[t + 64 * m];
                const float pa = pr ? p.z : p.x;
                const float pb = pr ? p.w : p.y;
                const float xxa = xr[j0][m] * xr[j0][m] + xi[j0][m] * xi[j0][m];
                const float Ra = xxa * pa + 2.f * pe[m] + 1e-10f;
                const float ia = 1.f / Ra;
                const float kra = pa * xr[j0][m] * ia, kia = -pa * xi[j0][m] * ia;
                const float a_r = kra * er[m] - kia * ei[m];
                const float a_i = kra * ei[m] + kia * er[m];
                const float xxb = xr[j1][m] * xr[j1][m] + xi[j1][m] * xi[j1][m];
                const float Rb = xxb * pb + 2.f * pe[m] + 1e-10f;
                const float ib = 1.f / Rb;
                const float krb = pb * xr[j1][m] * ib, kib = -pb * xi[j1][m] * ib;
                const float b_r = krb * er[m] - kib * ei[m];
                const float b_i = krb * ei[m] + kib * er[m];
                ur[m] = a_r - b_i;  ui[m] = a_i + b_r;   // KE0 + i*KE1
                gr[m] = a_r + b_i;  gi[m] = b_r - a_i;   // conj-pack for mirror lanes
            }
#pragma unroll
            for (int m = 4; m < 8; ++m) {
                ur[m] = __shfl(gr[7 - m], ml);
                ui[m] = __shfl(gi[7 - m], ml);
            }
            if (t == 0) {
                ur[5] = gr[3]; ui[5] = gi[3];
                ur[6] = gr[2]; ui[6] = gi[2];
                ur[7] = gr[1]; ui[7] = gi[1];
                const float Rn0 = xn[j0] * xn[j0] * pn[j0] + 2.f * pen + 1e-10f;
                const float Rn1 = xn[j1] * xn[j1] * pn[j1] + 2.f * pen + 1e-10f;
                ur[4] = pn[j0] * xn[j0] / Rn0 * en;   // KE0[256] (real)
                ui[4] = pn[j1] * xn[j1] / Rn1 * en;   // KE1[256] (real)
            }
            fft512w<1>(ur, ui, buf, tw2, tw3, ra, t);  // -> 512*(dH0 + i*dH1)
            // mask n<256 (slots m<4), scale 1/512, FFT the still-packed pair
#pragma unroll
            for (int m = 0; m < 4; ++m) { ur[m] *= (1.0f / 512.0f); ui[m] *= (1.0f / 512.0f); }
#pragma unroll
            for (int m = 4; m < 8; ++m) { ur[m] = 0.f; ui[m] = 0.f; }
            fft512w<-1>(ur, ui, buf, tw2, tw3, ra, t);  // Z = fd_dH0 + i*fd_dH1
            // unpack at low slots: fd0 = (Z + conj(Zm))/2, fd1 = -i/2 (Z - conj(Zm));
            // accumulate D += X_j0*fd0 + X_j1*fd1
#pragma unroll
            for (int m = 0; m < 4; ++m) {
                float zmr = __shfl(ur[7 - m], ml);
                float zmi = __shfl(ui[7 - m], ml);
                if (t == 0) {
                    zmr = (m == 0) ? ur[0] : ur[8 - m];
                    zmi = (m == 0) ? ui[0] : ui[8 - m];
                }
                const float f0r = 0.5f * (ur[m] + zmr), f0i = 0.5f * (ui[m] - zmi);
                const float f1r = 0.5f * (ui[m] + zmi), f1i = -0.5f * (ur[m] - zmr);
                Dr[m] += xr[j0][m] * f0r - xi[j0][m] * f0i + xr[j1][m] * f1r - xi[j1][m] * f1i;
                Di[m] += xr[j0][m] * f0i + xi[j0][m] * f0r + xr[j1][m] * f1i + xi[j1][m] * f1r;
            }
            if (t == 0) dn += xn[j0] * ur[4] + xn[j1] * ui[4];  // fd_dH nyq: Re/Im of Z4
        }
    }

    // ---- enhanced = mic - SF*(est + irfft(D)[256:]) ;  est = mic - d ----
    {
        float o4[4];
        herm_ifft(Dr, Di, dn, o4);
        float* op = g_out + (size_t)elem * 256;
#pragma unroll
        for (int q = 0; q < 4; ++q)
            op[t + 64 * q] = mv[q] - SF * ((mv[q] - d4[q]) + o4[q]);
    }
}

extern "C" void kernel_launch(void* const* d_in, const int* in_sizes, int n_in,
                              void* d_out, int out_size, void* d_ws, size_t ws_size,
                              hipStream_t stream) {
    const float* mic  = (const float*)d_in[0];
    const float* lsb  = (const float*)d_in[1];
    const float* phie = (const float*)d_in[2];
    // d_in[3] = phi_f: dead for the 'enhanced' output
    const float* p1   = (const float*)d_in[4];
    const float* hr   = (const float*)d_in[5];
    const float* hi   = (const float*)d_in[6];
    float* out = (float*)d_out;

    const int B = in_sizes[0] / 256;  // N_MIC == 1
    pbfd_kernel<<<B, 64, 0, stream>>>(mic, lsb, phie, p1, hr, hi, out);
}

// Round 13
// 35.700 us; speedup vs baseline: 1.4057x; 1.4057x over previous
//
#include <hip/hip_runtime.h>
#include <math.h>

#define SF 0.99999f
#define PI2 6.283185307179586476925f
#define SWZ(c) ((c) ^ (((c) >> 4) & 15))
// compiler-only fence: orders same-wave LDS write/read phases (HW LDS pipe is
// in-order per wave; this stops compiler reordering).
#define LDSFENCE() asm volatile("" ::: "memory")

template<int SGN>
__device__ __forceinline__ void twmul(float& ur, float& ui, float c, float s) {
    const float ss = (SGN < 0) ? -s : s;
    const float r = ur * c - ui * ss;
    const float i = ui * c + ur * ss;
    ur = r; ui = i;
}

// 8-point DFT across registers. SGN=-1: forward; SGN=+1: inverse.
template<int SGN>
__device__ __forceinline__ void bfly8(float* ur, float* ui) {
    const float C2 = 0.70710678118654752440f;
    float ar[4], ai[4], br[4], bi[4];
#pragma unroll
    for (int m = 0; m < 4; ++m) {
        ar[m] = ur[m] + ur[m + 4]; ai[m] = ui[m] + ui[m + 4];
        br[m] = ur[m] - ur[m + 4]; bi[m] = ui[m] - ui[m + 4];
    }
    float b1r, b1i, b2r, b2i, b3r, b3i;
    if (SGN < 0) {
        b1r = C2 * (br[1] + bi[1]); b1i = C2 * (bi[1] - br[1]);
        b2r = bi[2];                b2i = -br[2];
        b3r = C2 * (bi[3] - br[3]); b3i = -C2 * (br[3] + bi[3]);
    } else {
        b1r = C2 * (br[1] - bi[1]); b1i = C2 * (bi[1] + br[1]);
        b2r = -bi[2];               b2i = br[2];
        b3r = -C2 * (br[3] + bi[3]); b3i = C2 * (br[3] - bi[3]);
    }
    const float e0r = ar[0] + ar[2], e0i = ai[0] + ai[2];
    const float e1r = ar[0] - ar[2], e1i = ai[0] - ai[2];
    const float o0r = ar[1] + ar[3], o0i = ai[1] + ai[3];
    const float o1r = ar[1] - ar[3], o1i = ai[1] - ai[3];
    ur[0] = e0r + o0r; ui[0] = e0i + o0i;
    ur[4] = e0r - o0r; ui[4] = e0i - o0i;
    if (SGN < 0) { ur[2] = e1r + o1i; ui[2] = e1i - o1r; ur[6] = e1r - o1i; ui[6] = e1i + o1r; }
    else         { ur[2] = e1r - o1i; ui[2] = e1i + o1r; ur[6] = e1r + o1i; ui[6] = e1i - o1r; }
    const float f0r = br[0] + b2r, f0i = bi[0] + b2i;
    const float f1r = br[0] - b2r, f1i = bi[0] - b2i;
    const float g0r = b1r + b3r, g0i = b1i + b3i;
    const float g1r = b1r - b3r, g1i = b1i - b3i;
    ur[1] = f0r + g0r; ui[1] = f0i + g0i;
    ur[5] = f0r - g0r; ui[5] = f0i - g0i;
    if (SGN < 0) { ur[3] = f1r + g1i; ui[3] = f1i - g1r; ur[7] = f1r - g1i; ui[7] = f1i + g1r; }
    else         { ur[3] = f1r - g1i; ui[3] = f1i + g1r; ur[7] = f1r + g1i; ui[7] = f1i - g1r; }
}

// Wave-local 512-pt complex FFT, Stockham radix-8, 3 stages, single LDS buffer.
// ra[8] = hoisted read indices SWZ(t+64m). Writes per-element inline SWZ.
// No barriers (single-wave workgroup; LDS ops retire in order per wave).
template<int SGN>
__device__ __forceinline__ void fft512w(float* ur, float* ui,
                                        float2* __restrict__ buf,
                                        const float2* __restrict__ tw2,
                                        const float2* __restrict__ tw3,
                                        const int* ra, int t) {
    bfly8<SGN>(ur, ui);
    LDSFENCE();
#pragma unroll
    for (int m = 0; m < 8; ++m) buf[SWZ(8 * t + m)] = make_float2(ur[m], ui[m]);
    LDSFENCE();
#pragma unroll
    for (int m = 0; m < 8; ++m) { const float2 v = buf[ra[m]]; ur[m] = v.x; ui[m] = v.y; }
    const int k2 = t & 7;
#pragma unroll
    for (int m = 1; m < 8; ++m) { const float2 w = tw2[m * 8 + k2]; twmul<SGN>(ur[m], ui[m], w.x, w.y); }
    bfly8<SGN>(ur, ui);
    const int jj = ((t >> 3) << 6) + k2;
    LDSFENCE();
#pragma unroll
    for (int m = 0; m < 8; ++m) buf[SWZ(jj + 8 * m)] = make_float2(ur[m], ui[m]);
    LDSFENCE();
#pragma unroll
    for (int m = 0; m < 8; ++m) { const float2 v = buf[ra[m]]; ur[m] = v.x; ui[m] = v.y; }
#pragma unroll
    for (int m = 1; m < 8; ++m) { const float2 w = tw3[m * 64 + t]; twmul<SGN>(ur[m], ui[m], w.x, w.y); }
    bfly8<SGN>(ur, ui);
    LDSFENCE();
}

// ONE WAVE PER BLOCK, spill-free bound: (64,2) implies VGPR cap 256 -> allocator
// takes its natural ~92 (R9 body). No __syncthreads anywhere.
__global__ __launch_bounds__(64, 2) void pbfd_kernel(
    const float* __restrict__ g_mic,   // (B,256)
    const float* __restrict__ g_lsb,   // (B,1280)
    const float* __restrict__ g_phie,  // (B,257)
    const float* __restrict__ g_p1,    // (B,257,4)
    const float* __restrict__ g_hr,    // (B,257,4)
    const float* __restrict__ g_hi,    // (B,257,4)
    float* __restrict__ g_out)         // (B,256)
{
    __shared__ float2 tw2[64];
    __shared__ float2 tw3[512];
    __shared__ float2 xch[512];

    const int t = threadIdx.x;         // 0..63
    const int elem = blockIdx.x;
    float2* buf = &xch[0];
    const int ml = (64 - t) & 63;  // mirror lane: bin 512-k lives at (ml, 7-m) for t>=1

    // ---- per-block twiddle tables, built by this wave (no barrier needed) ----
    // tw3[m*64+t] = e^{+2pi i m t/512} via 7 iterated cmuls (accuracy validated R7);
    // tw2[l] = e^{+2pi i (l>>3)(l&7)/64}, one entry per lane.
    {
        float s3, c3;
        sincosf(PI2 * (float)t * (1.0f / 512.0f), &s3, &c3);
        float cr = 1.f, ci = 0.f;
#pragma unroll
        for (int m = 0; m < 8; ++m) {
            tw3[m * 64 + t] = make_float2(cr, ci);
            const float nr = cr * c3 - ci * s3;
            ci = ci * c3 + cr * s3;
            cr = nr;
        }
        float s2, c2;
        sincosf(PI2 * (float)((t >> 3) * (t & 7)) * (1.0f / 64.0f), &s2, &c2);
        tw2[t] = make_float2(c2, s2);
    }
    LDSFENCE();

    // ---- hoisted LDS read indices (invariant across all 9 FFTs) ----
    int ra[8];
#pragma unroll
    for (int m = 0; m < 8; ++m) ra[m] = SWZ(t + 64 * m);

    float mv[4];
    {
        const float* mp = g_mic + (size_t)elem * 256;
#pragma unroll
        for (int q = 0; q < 4; ++q) mv[q] = mp[t + 64 * q];
    }

    // ---- X: 4 real frame-FFTs as 2 paired complex FFTs; keep low bins + lane0 Nyquist ----
    float xr[4][4], xi[4][4], xn[4];
    {
        const float* lb = g_lsb + (size_t)elem * 1280;
#pragma unroll
        for (int pr = 0; pr < 2; ++pr) {
            float ur[8], ui[8];
#pragma unroll
            for (int m = 0; m < 8; ++m) {
                ur[m] = lb[(2 * pr) * 256 + t + 64 * m];
                ui[m] = lb[(2 * pr + 1) * 256 + t + 64 * m];
            }
            fft512w<-1>(ur, ui, buf, tw2, tw3, ra, t);
#pragma unroll
            for (int m = 0; m < 4; ++m) {
                float zmr = __shfl(ur[7 - m], ml);
                float zmi = __shfl(ui[7 - m], ml);
                if (t == 0) {  // lane0: mirror of bin 64m is slot 8-m (self for m=0)
                    zmr = (m == 0) ? ur[0] : ur[8 - m];
                    zmi = (m == 0) ? ui[0] : ui[8 - m];
                }
                xr[2 * pr][m]     = 0.5f * (ur[m] + zmr);
                xi[2 * pr][m]     = 0.5f * (ui[m] - zmi);
                xr[2 * pr + 1][m] = 0.5f * (ui[m] + zmi);
                xi[2 * pr + 1][m] = -0.5f * (ur[m] - zmr);
            }
            if (t == 0) { xn[2 * pr] = ur[4]; xn[2 * pr + 1] = ui[4]; }  // X[256] re/im-packed
        }
    }

    // Hermitian IFFT of a low-half spectrum (cr/ci low slots + lane0 Nyquist cn):
    // o4[q] = Re(ifft)[256+t+64q]/512.
    auto herm_ifft = [&](const float cr[4], const float ci[4], float cn, float o4[4]) {
        float ur[8], ui[8];
#pragma unroll
        for (int m = 0; m < 4; ++m) { ur[m] = cr[m]; ui[m] = ci[m]; }
#pragma unroll
        for (int m = 4; m < 8; ++m) {  // high slot = conj(mirror-lane low slot 7-m)
            ur[m] = __shfl(cr[7 - m], ml);
            ui[m] = -__shfl(ci[7 - m], ml);
        }
        if (t == 0) {
            ur[5] = cr[3]; ui[5] = -ci[3];
            ur[6] = cr[2]; ui[6] = -ci[2];
            ur[7] = cr[1]; ui[7] = -ci[1];
            ur[4] = cn; ui[4] = 0.f;  // Nyquist: real
        }
        fft512w<1>(ur, ui, buf, tw2, tw3, ra, t);
#pragma unroll
        for (int q = 0; q < 4; ++q) o4[q] = ur[4 + q] * (1.0f / 512.0f);
    };

    // ---- est (H prior): C = sum_j X*H; d = mic - est.  H dies after this block. ----
    float d4[4];
    float pn[4], en = 0.f, pen = 0.f;  // lane0 side channel
    {
        float hr_[4][4], hi_[4][4], hn[4];
        {
            const float4* hr4 = (const float4*)g_hr + (size_t)elem * 257;
            const float4* hi4 = (const float4*)g_hi + (size_t)elem * 257;
#pragma unroll
            for (int m = 0; m < 4; ++m) {
                const float4 a = hr4[t + 64 * m];
                hr_[0][m] = a.x; hr_[1][m] = a.y; hr_[2][m] = a.z; hr_[3][m] = a.w;
            }
#pragma unroll
            for (int m = 0; m < 4; ++m) {
                const float4 b = hi4[t + 64 * m];
                hi_[0][m] = b.x; hi_[1][m] = b.y; hi_[2][m] = b.z; hi_[3][m] = b.w;
            }
            if (t == 0) {
                const float4 a = hr4[256];
                const float4 p = ((const float4*)g_p1)[(size_t)elem * 257 + 256];
                hn[0] = a.x; hn[1] = a.y; hn[2] = a.z; hn[3] = a.w;
                pn[0] = p.x; pn[1] = p.y; pn[2] = p.z; pn[3] = p.w;
            }
        }
        float cr[4], ci[4], cn = 0.f;
#pragma unroll
        for (int m = 0; m < 4; ++m) {
            float sr = 0.f, si = 0.f;
#pragma unroll
            for (int j = 0; j < 4; ++j) {
                sr += xr[j][m] * hr_[j][m] - xi[j][m] * hi_[j][m];
                si += xr[j][m] * hi_[j][m] + xi[j][m] * hr_[j][m];
            }
            cr[m] = sr; ci[m] = si;
        }
        if (t == 0) {
#pragma unroll
            for (int j = 0; j < 4; ++j) cn += xn[j] * hn[j];
        }
        float o4[4];
        herm_ifft(cr, ci, cn, o4);
#pragma unroll
        for (int q = 0; q < 4; ++q) d4[q] = mv[q] - o4[q];
    }

    // ---- E = FFT([zeros(256); d]) ----
    float er[4], ei[4];
    {
        float ur[8], ui[8];
#pragma unroll
        for (int m = 0; m < 4; ++m) { ur[m] = 0.f; ui[m] = 0.f; }
#pragma unroll
        for (int q = 0; q < 4; ++q) { ur[4 + q] = d4[q]; ui[4 + q] = 0.f; }
        fft512w<-1>(ur, ui, buf, tw2, tw3, ra, t);
#pragma unroll
        for (int m = 0; m < 4; ++m) { er[m] = ur[m]; ei[m] = ui[m]; }
        if (t == 0) en = ur[4];
    }

    // ---- phi_e ----
    float pe[4];
    {
        const float* php = g_phie + (size_t)elem * 257;
#pragma unroll
        for (int m = 0; m < 4; ++m)
            pe[m] = 0.7f * php[t + 64 * m] + 0.3f * (er[m] * er[m] + ei[m] * ei[m]);
        if (t == 0) pen = 0.7f * php[256] + 0.3f * en * en;
    }

    // ---- gradient: pairs (0,1),(2,3): IFFT(KE0+i*KE1) -> mask -> FFT ->
    //      unpack fd_dH and accumulate D = sum_j X_j * fd_dH_j on the fly ----
    float Dr[4] = {0, 0, 0, 0}, Di[4] = {0, 0, 0, 0};
    float dn = 0.f;  // lane0: D at Nyquist
    {
        const float4* p14 = (const float4*)g_p1 + (size_t)elem * 257;
#pragma unroll
        for (int pr = 0; pr < 2; ++pr) {
            const int j0 = 2 * pr, j1 = 2 * pr + 1;
            float ur[8], ui[8], gr[4], gi[4];
#pragma unroll
            for (int m = 0; m < 4; ++m) {
                // KE_j = P1_j * conj(X_j) / R_j * E  (P1 reloaded here, cache-hot)
                const float4 p = p14[t + 64 * m];
                const float pa = pr ? p.z : p.x;
                const float pb = pr ? p.w : p.y;
                const float xxa = xr[j0][m] * xr[j0][m] + xi[j0][m] * xi[j0][m];
                const float Ra = xxa * pa + 2.f * pe[m] + 1e-10f;
                const float ia = 1.f / Ra;
                const float kra = pa * xr[j0][m] * ia, kia = -pa * xi[j0][m] * ia;
                const float a_r = kra * er[m] - kia * ei[m];
                const float a_i = kra * ei[m] + kia * er[m];
                const float xxb = xr[j1][m] * xr[j1][m] + xi[j1][m] * xi[j1][m];
                const float Rb = xxb * pb + 2.f * pe[m] + 1e-10f;
                const float ib = 1.f / Rb;
                const float krb = pb * xr[j1][m] * ib, kib = -pb * xi[j1][m] * ib;
                const float b_r = krb * er[m] - kib * ei[m];
                const float b_i = krb * ei[m] + kib * er[m];
                ur[m] = a_r - b_i;  ui[m] = a_i + b_r;   // KE0 + i*KE1
                gr[m] = a_r + b_i;  gi[m] = b_r - a_i;   // conj-pack for mirror lanes
            }
#pragma unroll
            for (int m = 4; m < 8; ++m) {
                ur[m] = __shfl(gr[7 - m], ml);
                ui[m] = __shfl(gi[7 - m], ml);
            }
            if (t == 0) {
                ur[5] = gr[3]; ui[5] = gi[3];
                ur[6] = gr[2]; ui[6] = gi[2];
                ur[7] = gr[1]; ui[7] = gi[1];
                const float Rn0 = xn[j0] * xn[j0] * pn[j0] + 2.f * pen + 1e-10f;
                const float Rn1 = xn[j1] * xn[j1] * pn[j1] + 2.f * pen + 1e-10f;
                ur[4] = pn[j0] * xn[j0] / Rn0 * en;   // KE0[256] (real)
                ui[4] = pn[j1] * xn[j1] / Rn1 * en;   // KE1[256] (real)
            }
            fft512w<1>(ur, ui, buf, tw2, tw3, ra, t);  // -> 512*(dH0 + i*dH1)
            // mask n<256 (slots m<4), scale 1/512, FFT the still-packed pair
#pragma unroll
            for (int m = 0; m < 4; ++m) { ur[m] *= (1.0f / 512.0f); ui[m] *= (1.0f / 512.0f); }
#pragma unroll
            for (int m = 4; m < 8; ++m) { ur[m] = 0.f; ui[m] = 0.f; }
            fft512w<-1>(ur, ui, buf, tw2, tw3, ra, t);  // Z = fd_dH0 + i*fd_dH1
            // unpack at low slots: fd0 = (Z + conj(Zm))/2, fd1 = -i/2 (Z - conj(Zm));
            // accumulate D += X_j0*fd0 + X_j1*fd1
#pragma unroll
            for (int m = 0; m < 4; ++m) {
                float zmr = __shfl(ur[7 - m], ml);
                float zmi = __shfl(ui[7 - m], ml);
                if (t == 0) {
                    zmr = (m == 0) ? ur[0] : ur[8 - m];
                    zmi = (m == 0) ? ui[0] : ui[8 - m];
                }
                const float f0r = 0.5f * (ur[m] + zmr), f0i = 0.5f * (ui[m] - zmi);
                const float f1r = 0.5f * (ui[m] + zmi), f1i = -0.5f * (ur[m] - zmr);
                Dr[m] += xr[j0][m] * f0r - xi[j0][m] * f0i + xr[j1][m] * f1r - xi[j1][m] * f1i;
                Di[m] += xr[j0][m] * f0i + xi[j0][m] * f0r + xr[j1][m] * f1i + xi[j1][m] * f1r;
            }
            if (t == 0) dn += xn[j0] * ur[4] + xn[j1] * ui[4];  // fd_dH nyq: Re/Im of Z4
        }
    }

    // ---- enhanced = mic - SF*(est + irfft(D)[256:]) ;  est = mic - d ----
    {
        float o4[4];
        herm_ifft(Dr, Di, dn, o4);
        float* op = g_out + (size_t)elem * 256;
#pragma unroll
        for (int q = 0; q < 4; ++q)
            op[t + 64 * q] = mv[q] - SF * ((mv[q] - d4[q]) + o4[q]);
    }
}

extern "C" void kernel_launch(void* const* d_in, const int* in_sizes, int n_in,
                              void* d_out, int out_size, void* d_ws, size_t ws_size,
                              hipStream_t stream) {
    const float* mic  = (const float*)d_in[0];
    const float* lsb  = (const float*)d_in[1];
    const float* phie = (const float*)d_in[2];
    // d_in[3] = phi_f: dead for the 'enhanced' output
    const float* p1   = (const float*)d_in[4];
    const float* hr   = (const float*)d_in[5];
    const float* hi   = (const float*)d_in[6];
    float* out = (float*)d_out;

    const int B = in_sizes[0] / 256;  // N_MIC == 1
    pbfd_kernel<<<B, 64, 0, stream>>>(mic, lsb, phie, p1, hr, hi, out);
}